// Round 2
// baseline (547.750 us; speedup 1.0000x reference)
//
#include <hip/hip_runtime.h>

// Pair feature expansion: out[i*512+j] = concat(x_i[0:260], x_j[0:260], r1, r2)
// n=512, d=260, row = 522 floats = 261 float2 (row base always 8B-aligned).
//
// R4 theory: R2/R3 were limited not by store shape but by store DUTY CYCLE —
// 16 waves/CU (33KB LDS) each issuing only ~8 store instrs between a
// __syncthreads() (HIP drains vmcnt(0) at barriers) and the endpgm vmcnt(0)
// drain. The fill kernel that hits 6.27 TB/s is a barrier-free 32-wave/CU
// grid-stride store loop. So: mimic it exactly.
//
// Structure: NO LDS, NO barriers. Output viewed as flat float2[m]:
//   row = m / 261 (magic div), s = m % 261, i = row>>9, j = row&511
//   s < 130  -> x_i f2[s]          (L2-resident broadcast row)
//   s < 260  -> x_j f2[s-130]      (L2-resident, input = 532 KB total)
//   s == 260 -> (r1, r2) computed inline under exec mask (rare: 1 lane/4 waves)
// Per thread: 130.5 f2, processed in groups of 4, software-pipelined one
// group ahead (load g+1 issued BEFORE stores of g) so every load-wait is a
// counted vmcnt with all stores YOUNGER in the FIFO -> stores are never
// drained mid-kernel. vmcnt(0) happens once, at endpgm.

#define N 512
#define D 260
#define RPF2 261
#define TOTF2 (N * N * RPF2)      // 68,419,584 = 130.5 * TT exactly
#define NBLK 2048
#define NTHR 256
#define TT (NBLK * NTHR)          // 524,288 threads

__device__ __forceinline__ float2 pair_src(const float* __restrict__ in, unsigned m) {
    // m / 261 via round-up magic: M = ceil(2^34/261) = 65823254, e = 110,
    // exact for m < 2^34/110 = 156M > 68.4M.
    const unsigned row = (unsigned)(((unsigned long long)m * 65823254ull) >> 34);
    const unsigned s   = m - row * RPF2;
    const unsigned i   = row >> 9;
    const unsigned j   = row & (N - 1);

    const bool     fi  = (s < 130u);
    const unsigned sj  = s - 130u;                       // garbage when fi
    const unsigned ri  = fi ? i : j;
    const unsigned off = fi ? s : (sj < 130u ? sj : 0u); // clamp s==260 to safe addr
    float2 v = *(const float2*)(in + ri * D + 2u * off);

    if (s == 260u) {  // rare masked path: compute (r1, r2)
        const float* bi = in + i * D + 256;
        const float* bj = in + j * D + 256;
        const float2 bi0 = *(const float2*)bi, bi1 = *(const float2*)(bi + 2);
        const float2 bj0 = *(const float2*)bj, bj1 = *(const float2*)(bj + 2);
        const float ww = fmaxf(0.f, fminf(bi1.x, bj1.x) - fmaxf(bi0.x, bj0.x));
        const float hh = fmaxf(0.f, fminf(bi1.y, bj1.y) - fmaxf(bi0.y, bj0.y));
        const float inter = ww * hh;
        v = make_float2(inter / ((bi1.x - bi0.x) * (bi1.y - bi0.y)),
                        inter / ((bj1.x - bj0.x) * (bj1.y - bj0.y)));
    }
    return v;
}

__global__ __launch_bounds__(NTHR) void pair_kernel(const float* __restrict__ in,
                                                    float* __restrict__ out) {
    const unsigned T = blockIdx.x * NTHR + threadIdx.x;
    float2* __restrict__ o2 = (float2*)out;

    // group q = f2 indices m = (4q+u)*TT + T, u=0..3. Groups 0..31 cover
    // k=0..127; tail handles k=128..130 (k=130 is the half-group).
    float2 a0, a1, a2, a3, b0, b1, b2, b3;

#define LOADG(r0, r1, r2, r3, q)                          \
    r0 = pair_src(in, (unsigned)(4 * (q) + 0) * TT + T);  \
    r1 = pair_src(in, (unsigned)(4 * (q) + 1) * TT + T);  \
    r2 = pair_src(in, (unsigned)(4 * (q) + 2) * TT + T);  \
    r3 = pair_src(in, (unsigned)(4 * (q) + 3) * TT + T);
#define STORG(r0, r1, r2, r3, q)                          \
    o2[(unsigned)(4 * (q) + 0) * TT + T] = r0;            \
    o2[(unsigned)(4 * (q) + 1) * TT + T] = r1;            \
    o2[(unsigned)(4 * (q) + 2) * TT + T] = r2;            \
    o2[(unsigned)(4 * (q) + 3) * TT + T] = r3;

    LOADG(a0, a1, a2, a3, 0)
    LOADG(b0, b1, b2, b3, 1)
    STORG(a0, a1, a2, a3, 0)          // waits L(g0) only; L(g1) younger, ok

    #pragma unroll 1                  // keep rolled: I-cache + stable schedule
    for (int t = 0; t < 15; ++t) {
        const int q = 2 * t + 2;
        LOADG(a0, a1, a2, a3, q)      // issue loads BEFORE stores of q-1
        STORG(b0, b1, b2, b3, q - 1)  // wait L(q-1): oldest in FIFO -> counted
        LOADG(b0, b1, b2, b3, q + 1)
        STORG(a0, a1, a2, a3, q)
    }
    STORG(b0, b1, b2, b3, 31)

    // tail: k = 128, 129 full; k = 130 valid for T < TT/2
    #pragma unroll 1
    for (unsigned k = 128; k <= 130; ++k) {
        const unsigned m = k * TT + T;
        if (m < TOTF2) o2[m] = pair_src(in, m);
    }
#undef LOADG
#undef STORG
}

extern "C" void kernel_launch(void* const* d_in, const int* in_sizes, int n_in,
                              void* d_out, int out_size, void* d_ws, size_t ws_size,
                              hipStream_t stream) {
    const float* in = (const float*)d_in[0];
    float* out = (float*)d_out;
    pair_kernel<<<NBLK, NTHR, 0, stream>>>(in, out);
}

// Round 3
// 534.436 us; speedup vs baseline: 1.0249x; 1.0249x over previous
//
#include <hip/hip_runtime.h>

// Pair feature expansion: out[i*512+j] = concat(x_i[0:260], x_j[0:260], r1, r2)
// n=512, d=260, out row = 522 floats (2088 B). Output 547 MB -> pure write-bound.
//
// R5 = R3 structure (best measured: 530.0 µs) at 512 threads/block.
// Evidence so far: three structurally different kernels (R2 f2-stores, R3
// LDS-image + fill-shaped f4 stream, R4 barrier-free streaming) all land at
// 530-548 µs total. Store shape, barriers, vmcnt discipline all ruled out as
// limiters. Best remaining reading: timed graph = poison fill (350 µs) +
// ~dozens of tiny reset memsets (~90 µs) + pair kernel (~90 µs ~= 87 µs write
// roofline). This round doubles occupancy (16 -> 32 waves/CU; LDS 33.4 KB
// still allows 4 blocks/CU at 512 thr) to kill the last alternative theory
// (phase-A/phase-B serialization). If neutral -> pair is at roofline.
//
// LDS image layout per row (float2 slots, 261 per row):
//   slot 0..63    = x_i[0:128]     (regs xi_a)
//   slot 64..127  = x_i[128:256]   (regs xi_b)
//   slot 128..129 = x_i bbox       (regs bb)
//   slot 130..193 = x_j[0:128]     (global, L2-resident)
//   slot 194..257 = x_j[128:256]   (global)
//   slot 258..259 = x_j bbox       (global)
//   slot 260      = (r1, r2)       (computed by lane 2)

#define N 512
#define D 260
#define JT 16
#define ROW 522
#define NTHR 512
#define REG_F4 (JT * ROW / 4)   // 2088 float4 per block region

__global__ __launch_bounds__(NTHR) void pair_kernel(const float* __restrict__ in,
                                                    float* __restrict__ out) {
    const int b    = blockIdx.x;
    const int i    = b >> 5;            // 32 j-tiles per i
    const int j0   = (b & 31) * JT;
    const int tid  = threadIdx.x;
    const int lane = tid & 63;
    const int w    = tid >> 6;          // 0..7

    __shared__ __align__(16) float s_img[JT * ROW];

    // x_i sources live in registers (broadcast row, L2-resident).
    const float* rowi = in + i * D;
    const float2 xi_a = ((const float2*)rowi)[lane];        // x_i[2l..2l+1]
    const float2 xi_b = ((const float2*)rowi)[64 + lane];   // x_i[128+2l..]
    const float4 bb   = *(const float4*)(rowi + 256);       // x_i bbox

    // ---- Phase A: build the 16-row image in LDS. All global loads here. ----
    for (int lj = w; lj < JT; lj += 8) {   // 2 rows per wave
        const float* xjrow = in + (size_t)(j0 + lj) * D;
        const float2 ga = ((const float2*)xjrow)[lane];        // x_j[2l..2l+1]
        const float2 gb = ((const float2*)xjrow)[64 + lane];   // x_j[128+2l..]
        float2* row2 = (float2*)(s_img + lj * ROW);            // 8B-aligned

        row2[lane]       = xi_a;
        row2[64 + lane]  = xi_b;
        row2[130 + lane] = ga;
        row2[194 + lane] = gb;
        if (lane < 2) {
            row2[128 + lane] = lane ? make_float2(bb.z, bb.w)
                                    : make_float2(bb.x, bb.y);
            row2[258 + lane] = ((const float2*)xjrow)[128 + lane];  // x_j bbox
        }
        if (lane == 2) {
            const float4 bj = *(const float4*)(xjrow + 256);
            const float ww = fmaxf(0.0f, fminf(bb.z, bj.z) - fmaxf(bb.x, bj.x));
            const float hh = fmaxf(0.0f, fminf(bb.w, bj.w) - fmaxf(bb.y, bj.y));
            const float inter = ww * hh;
            row2[260] = make_float2(inter / ((bb.z - bb.x) * (bb.w - bb.y)),
                                    inter / ((bj.z - bj.x) * (bj.w - bj.y)));
        }
    }
    __syncthreads();

    // ---- Phase B: pure aligned float4 store stream (fill-kernel shape). ----
    const float4* s4 = (const float4*)s_img;
    float4* o4 = (float4*)(out + (size_t)(i * N + j0) * ROW);  // 64B-aligned

    int t = tid;
    #pragma unroll
    for (int k = 0; k < 4; ++k, t += NTHR) {   // 4 * 512 = 2048 float4
        o4[t] = s4[t];
    }
    if (t < REG_F4) o4[t] = s4[t];             // tail: 40 float4 (tid < 40)
}

extern "C" void kernel_launch(void* const* d_in, const int* in_sizes, int n_in,
                              void* d_out, int out_size, void* d_ws, size_t ws_size,
                              hipStream_t stream) {
    const float* in = (const float*)d_in[0];
    float* out = (float*)d_out;
    pair_kernel<<<N * (N / JT), NTHR, 0, stream>>>(in, out);
}